// Round 22
// baseline (436.055 us; speedup 1.0000x reference)
//
#include <hip/hip_runtime.h>
#include <math.h>

typedef unsigned short u16;
typedef short short8 __attribute__((ext_vector_type(8)));
typedef float f32x4 __attribute__((ext_vector_type(4)));
typedef unsigned short ushort4v __attribute__((ext_vector_type(4)));

#define Hh 256
#define Ww 256
#define Bb 8
#define PW 262
#define PAD 3
#define HPW (Hh * PW)

__device__ __forceinline__ float bf2f(u16 v) {
    unsigned u = ((unsigned)v) << 16;
    union { unsigned u; float f; } c; c.u = u; return c.f;
}
__device__ __forceinline__ u16 f2bf(float f) {
    union { float f; unsigned u; } c; c.f = f;
    unsigned lsb = (c.u >> 16) & 1u;
    c.u += 0x7fffu + lsb;
    return (u16)(c.u >> 16);
}
__device__ __forceinline__ float sigm(float v) { return 1.f / (1.f + expf(-v)); }

// ============ 3x3 conv, 2 rows/block, B staged in LDS (4 rows) ============
// FUSEP: f output (lrelu) -> LDS tile; 1x1 over concat(O0, tile) -> pout.
template<int ACT, bool F32OUT, bool FUSEP>
__global__ __launch_bounds__(256) void convs_k(
    const u16* __restrict__ in, const u16* __restrict__ apack,
    const float* __restrict__ bias, void* __restrict__ outp,
    const u16* __restrict__ o0buf, const u16* __restrict__ pw,
    const float* __restrict__ pb, u16* __restrict__ pout)
{
    __shared__ u16 rows[4][4352];   // 34816 B; rows[0..1] reused as f tile
    const int tid = threadIdx.x, lane = tid & 63, wv = tid >> 6;
    const int b = blockIdx.x & 7;
    const int rest = blockIdx.x >> 3;        // 0..255
    const int hpair = rest >> 1, half = rest & 1;
    const int h0 = hpair * 2;
    const int pl = wv * 32 + (lane & 15);
    const int icg = lane >> 4;

    for (int idx = tid; idx < 4 * 536; idx += 256) {
        int rr = idx / 536, q = idx % 536;
        int r = h0 - 1 + rr;
        short8 v = (short8){0, 0, 0, 0, 0, 0, 0, 0};
        if ((unsigned)r < 256u)
            v = *(const short8*)(in + ((size_t)b * HPW + (size_t)r * PW + PAD + half * 128 - 3) * 32
                                 + (size_t)q * 8);
        *(short8*)(&rows[rr][q * 8]) = v;
    }
    __syncthreads();

    f32x4 acc[2][2][2];   // [row][mf][nf]
    #pragma unroll
    for (int r2 = 0; r2 < 2; ++r2)
        #pragma unroll
        for (int mf = 0; mf < 2; ++mf)
            #pragma unroll
            for (int nf = 0; nf < 2; ++nf)
                acc[r2][mf][nf] = (f32x4){0.f, 0.f, 0.f, 0.f};

    #pragma unroll
    for (int tap = 0; tap < 9; ++tap) {
        const int kh = tap / 3 - 1, kw = tap % 3 - 1;
        short8 a0 = *(const short8*)(apack + ((size_t)(tap * 2 + 0) * 64 + lane) * 8);
        short8 a1 = *(const short8*)(apack + ((size_t)(tap * 2 + 1) * 64 + lane) * 8);
        #pragma unroll
        for (int r2 = 0; r2 < 2; ++r2) {
            const int ri = 1 + r2 + kh;   // 0..3
            #pragma unroll
            for (int nf = 0; nf < 2; ++nf) {
                short8 bf = *(const short8*)(&rows[ri][(pl + nf * 16 + kw + 3) * 32 + icg * 8]);
                acc[r2][0][nf] = __builtin_amdgcn_mfma_f32_16x16x32_bf16(a0, bf, acc[r2][0][nf], 0, 0, 0);
                acc[r2][1][nf] = __builtin_amdgcn_mfma_f32_16x16x32_bf16(a1, bf, acc[r2][1][nf], 0, 0, 0);
            }
        }
    }
    const int nl = half * 128 + pl;
    f32x4 bi[2];
    bi[0] = *(const f32x4*)(bias + icg * 4);
    bi[1] = *(const f32x4*)(bias + 16 + icg * 4);

    if (FUSEP) {
        u16* tile = &rows[0][0];
        __syncthreads();
        #pragma unroll
        for (int r2 = 0; r2 < 2; ++r2)
            #pragma unroll
            for (int mf = 0; mf < 2; ++mf) {
                const int cob = mf * 16 + icg * 4;
                #pragma unroll
                for (int nf = 0; nf < 2; ++nf) {
                    ushort4v o;
                    #pragma unroll
                    for (int i = 0; i < 4; ++i) {
                        float v = acc[r2][mf][nf][i] + bi[mf][i];
                        v = (v > 0.f) ? v : 0.01f * v;
                        o[i] = f2bf(v);
                    }
                    *(ushort4v*)(tile + ((size_t)(r2 * 128 + pl + nf * 16)) * 32 + cob) = o;
                }
            }
        __syncthreads();
        #pragma unroll
        for (int r2 = 0; r2 < 2; ++r2) {
            const int h = h0 + r2;
            f32x4 acc2[2][2];
            #pragma unroll
            for (int mf = 0; mf < 2; ++mf)
                #pragma unroll
                for (int nf = 0; nf < 2; ++nf)
                    acc2[mf][nf] = (f32x4){0.f, 0.f, 0.f, 0.f};
            #pragma unroll
            for (int s = 0; s < 2; ++s) {
                short8 pa0 = *(const short8*)(pw + (size_t)(s * 2 + 0) * 512 + lane * 8);
                short8 pa1 = *(const short8*)(pw + (size_t)(s * 2 + 1) * 512 + lane * 8);
                #pragma unroll
                for (int nf = 0; nf < 2; ++nf) {
                    const int px = pl + nf * 16;
                    short8 bf;
                    if (s == 0)
                        bf = *(const short8*)(o0buf + ((size_t)b * HPW + (size_t)h * PW + PAD + half * 128 + px) * 32 + icg * 8);
                    else
                        bf = *(const short8*)(tile + ((size_t)(r2 * 128 + px)) * 32 + icg * 8);
                    acc2[0][nf] = __builtin_amdgcn_mfma_f32_16x16x32_bf16(pa0, bf, acc2[0][nf], 0, 0, 0);
                    acc2[1][nf] = __builtin_amdgcn_mfma_f32_16x16x32_bf16(pa1, bf, acc2[1][nf], 0, 0, 0);
                }
            }
            const size_t orow = ((size_t)b * HPW + (size_t)h * PW + PAD) * 32;
            #pragma unroll
            for (int mf = 0; mf < 2; ++mf) {
                const int cob = mf * 16 + icg * 4;
                f32x4 pbi = *(const f32x4*)(pb + cob);
                #pragma unroll
                for (int nf = 0; nf < 2; ++nf) {
                    ushort4v o;
                    #pragma unroll
                    for (int i = 0; i < 4; ++i) {
                        float v = acc2[mf][nf][i] + pbi[i];
                        v = (v > 0.f) ? v : 0.01f * v;
                        o[i] = f2bf(v);
                    }
                    *(ushort4v*)(pout + orow + (size_t)(nl + nf * 16) * 32 + cob) = o;
                }
            }
        }
        if (tid < 24) {
            int r2 = tid / 12, rem = tid % 12;
            int col3 = rem >> 2, chunk = rem & 3;
            int col = half ? (256 + PAD + col3) : col3;
            u16* pz = pout + ((size_t)b * HPW + (size_t)(h0 + r2) * PW + col) * 32 + chunk * 8;
            *(short8*)pz = (short8){0, 0, 0, 0, 0, 0, 0, 0};
        }
    } else if (F32OUT) {
        #pragma unroll
        for (int r2 = 0; r2 < 2; ++r2) {
            float* dp = (float*)outp + ((size_t)b * 64 + 32) * 65536 + (size_t)(h0 + r2) * 256;
            #pragma unroll
            for (int mf = 0; mf < 2; ++mf) {
                const int cob = mf * 16 + icg * 4;
                #pragma unroll
                for (int nf = 0; nf < 2; ++nf) {
                    const int w = nl + nf * 16;
                    #pragma unroll
                    for (int i = 0; i < 4; ++i) {
                        float v = acc[r2][mf][nf][i] + bi[mf][i];
                        if (ACT == 1) v = fmaxf(v, 0.f);
                        if (ACT == 2) v = (v > 0.f) ? v : 0.01f * v;
                        dp[(size_t)(cob + i) * 65536 + w] = v;
                    }
                }
            }
        }
    } else {
        u16* out = (u16*)outp;
        #pragma unroll
        for (int r2 = 0; r2 < 2; ++r2) {
            const size_t orow = ((size_t)b * HPW + (size_t)(h0 + r2) * PW + PAD) * 32;
            #pragma unroll
            for (int mf = 0; mf < 2; ++mf) {
                const int cob = mf * 16 + icg * 4;
                #pragma unroll
                for (int nf = 0; nf < 2; ++nf) {
                    ushort4v o;
                    #pragma unroll
                    for (int i = 0; i < 4; ++i) {
                        float v = acc[r2][mf][nf][i] + bi[mf][i];
                        if (ACT == 1) v = fmaxf(v, 0.f);
                        if (ACT == 2) v = (v > 0.f) ? v : 0.01f * v;
                        o[i] = f2bf(v);
                    }
                    *(ushort4v*)(out + orow + (size_t)(nl + nf * 16) * 32 + cob) = o;
                }
            }
        }
    }
}

// ============ fused ec1/ec2/ec3 + gate, 2 rows/block ======================
// Center rows {h,h+1} staged once. Per phase d, halo slots:
//   s0 = h-d, s1 = h+1-d (d>=2), s2 = h+d (d>=2), s3 = h+1+d.
// Single halo buffer; next phase's halos prefetched to REGS during compute,
// written after a barrier, second barrier before next phase reads.
__global__ __launch_bounds__(256) void ecfuse_k(
    const u16* __restrict__ in, const u16* __restrict__ apack,
    const float* __restrict__ b1, const float* __restrict__ b2,
    const float* __restrict__ b3, const float* __restrict__ gw_,
    const float* __restrict__ gb_, u16* __restrict__ enh)
{
    __shared__ u16 crow[2][4288];       // rows h, h+1
    __shared__ u16 halo[4][4288];       // slots s0..s3
    __shared__ float gw[288];
    __shared__ float gb[3];
    __shared__ float bs[96];
    int tid = threadIdx.x;
    for (int i = tid; i < 288; i += 256) gw[i] = gw_[i];
    if (tid < 3) gb[tid] = gb_[tid];
    if (tid < 32) bs[tid] = b1[tid];
    else if (tid < 64) bs[tid] = b2[tid - 32];
    else if (tid < 96) bs[tid] = b3[tid - 64];

    const int lane = tid & 63, wv = tid >> 6;
    const int b = blockIdx.x & 7;
    const int rest = blockIdx.x >> 3;        // 0..255
    const int hpair = rest >> 1, half = rest & 1;
    const int h = hpair * 2;
    const int pl = wv * 32 + (lane & 15);
    const int icg = lane >> 4;
    const u16* src_base = in + ((size_t)b * HPW + PAD + half * 128 - 3) * 32;

    // initial staging: center rows h,h+1 and d=1 halos (s0 = h-1, s3 = h+2)
    for (int idx = tid; idx < 4 * 536; idx += 256) {
        int rr = idx / 536, q = idx % 536;   // rr: 0->h-1(s0) 1->h 2->h+1 3->h+2(s3)
        int r = h - 1 + rr;
        short8 v = (short8){0, 0, 0, 0, 0, 0, 0, 0};
        if ((unsigned)r < 256u)
            v = *(const short8*)(src_base + (size_t)r * PW * 32 + (size_t)q * 8);
        u16* dst = (rr == 1) ? &crow[0][q * 8] : (rr == 2) ? &crow[1][q * 8]
                 : (rr == 0) ? &halo[0][q * 8] : &halo[3][q * 8];
        *(short8*)dst = v;
    }
    __syncthreads();

    f32x4 acc[3][2][2][2];   // [cv][r2][mf][nf] = 96 VGPR
    #pragma unroll
    for (int cv = 0; cv < 3; ++cv)
        #pragma unroll
        for (int r2 = 0; r2 < 2; ++r2)
            #pragma unroll
            for (int mf = 0; mf < 2; ++mf)
                #pragma unroll
                for (int nf = 0; nf < 2; ++nf)
                    acc[cv][r2][mf][nf] = (f32x4){0.f, 0.f, 0.f, 0.f};

    #pragma unroll
    for (int cv = 0; cv < 3; ++cv) {
        const int dil = cv + 1;
        // prefetch next phase's 4 halo rows into regs (8 chunks + tail)
        short8 stg0, stg1, stg2, stg3, stg4, stg5, stg6, stg7, stgT;
        if (cv < 2) {
            const int dn = cv + 2;
            #pragma unroll
            for (int k = 0; k < 8; ++k) {
                int idx = tid + k * 256;            // < 2048 (of 2144)
                int rr = idx / 536, q = idx % 536;  // rr 0..3
                int off = (rr == 0) ? -dn : (rr == 1) ? 1 - dn : (rr == 2) ? dn : dn + 1;
                int r = h + off;
                short8 v = (short8){0, 0, 0, 0, 0, 0, 0, 0};
                if ((unsigned)r < 256u)
                    v = *(const short8*)(src_base + (size_t)r * PW * 32 + (size_t)q * 8);
                if (k == 0) stg0 = v; else if (k == 1) stg1 = v;
                else if (k == 2) stg2 = v; else if (k == 3) stg3 = v;
                else if (k == 4) stg4 = v; else if (k == 5) stg5 = v;
                else if (k == 6) stg6 = v; else stg7 = v;
            }
            if (tid < 96) {                         // idx 2048..2143, rr = 3
                int q = 440 + tid;
                int r = h + dn + 1;
                short8 v = (short8){0, 0, 0, 0, 0, 0, 0, 0};
                if ((unsigned)r < 256u)
                    v = *(const short8*)(src_base + (size_t)r * PW * 32 + (size_t)q * 8);
                stgT = v;
            }
        }
        // compute phase cv: row for (r2, kh): kh=0 -> crow[r2];
        //   kh=-1: r2=0 -> halo s0; r2=1 -> (d==1 ? crow[0] : halo s1)
        //   kh=+1: r2=0 -> (d==1 ? crow[1] : halo s2); r2=1 -> halo s3
        const u16* ap = apack + (size_t)(cv * 9 * 2) * 512;
        #pragma unroll
        for (int tap = 0; tap < 9; ++tap) {
            const int kh = tap / 3 - 1, kw = tap % 3 - 1;
            short8 a0 = *(const short8*)(ap + (size_t)(tap * 2 + 0) * 512 + lane * 8);
            short8 a1 = *(const short8*)(ap + (size_t)(tap * 2 + 1) * 512 + lane * 8);
            #pragma unroll
            for (int r2 = 0; r2 < 2; ++r2) {
                const u16* rp;
                if (kh == 0) rp = &crow[r2][0];
                else if (kh == -1) rp = (r2 == 0) ? &halo[0][0]
                                        : (dil == 1 ? &crow[0][0] : &halo[1][0]);
                else rp = (r2 == 1) ? &halo[3][0]
                          : (dil == 1 ? &crow[1][0] : &halo[2][0]);
                #pragma unroll
                for (int nf = 0; nf < 2; ++nf) {
                    short8 bf = *(const short8*)(rp + (pl + nf * 16 + kw * dil + 3) * 32 + icg * 8);
                    acc[cv][r2][0][nf] = __builtin_amdgcn_mfma_f32_16x16x32_bf16(a0, bf, acc[cv][r2][0][nf], 0, 0, 0);
                    acc[cv][r2][1][nf] = __builtin_amdgcn_mfma_f32_16x16x32_bf16(a1, bf, acc[cv][r2][1][nf], 0, 0, 0);
                }
            }
        }
        // commit prefetched halos
        if (cv < 2) {
            __syncthreads();   // all reads of halo done
            #pragma unroll
            for (int k = 0; k < 8; ++k) {
                int idx = tid + k * 256;
                int rr = idx / 536, q = idx % 536;
                short8 v = (k == 0) ? stg0 : (k == 1) ? stg1 : (k == 2) ? stg2
                         : (k == 3) ? stg3 : (k == 4) ? stg4 : (k == 5) ? stg5
                         : (k == 6) ? stg6 : stg7;
                *(short8*)(&halo[rr][q * 8]) = v;
            }
            if (tid < 96)
                *(short8*)(&halo[3][(440 + tid) * 8]) = stgT;
            __syncthreads();
        }
    }
    // epilogue: per row, gate softmax + blend + ENH write
    #pragma unroll
    for (int r2 = 0; r2 < 2; ++r2) {
        const int nl = half * 128 + pl;
        const size_t orow = ((size_t)b * HPW + (size_t)(h + r2) * PW + PAD) * 32;
        #pragma unroll
        for (int nf = 0; nf < 2; ++nf) {
            float e[3][2][4];
            float g0 = 0.f, g1 = 0.f, g2 = 0.f;
            #pragma unroll
            for (int cv = 0; cv < 3; ++cv)
                #pragma unroll
                for (int mf = 0; mf < 2; ++mf) {
                    const int cob = mf * 16 + icg * 4;
                    #pragma unroll
                    for (int i = 0; i < 4; ++i) {
                        float v = fmaxf(acc[cv][r2][mf][nf][i] + bs[cv * 32 + cob + i], 0.f);
                        e[cv][mf][i] = v;
                        const int c = cv * 32 + cob + i;
                        g0 = fmaf(gw[c], v, g0);
                        g1 = fmaf(gw[96 + c], v, g1);
                        g2 = fmaf(gw[192 + c], v, g2);
                    }
                }
            g0 += __shfl_xor(g0, 16); g0 += __shfl_xor(g0, 32);
            g1 += __shfl_xor(g1, 16); g1 += __shfl_xor(g1, 32);
            g2 += __shfl_xor(g2, 16); g2 += __shfl_xor(g2, 32);
            g0 += gb[0]; g1 += gb[1]; g2 += gb[2];
            float m = fmaxf(g0, fmaxf(g1, g2));
            float e0 = expf(g0 - m), e1 = expf(g1 - m), e2 = expf(g2 - m);
            float inv = 1.f / (e0 + e1 + e2);
            e0 *= inv; e1 *= inv; e2 *= inv;
            #pragma unroll
            for (int mf = 0; mf < 2; ++mf) {
                const int cob = mf * 16 + icg * 4;
                ushort4v o;
                #pragma unroll
                for (int i = 0; i < 4; ++i)
                    o[i] = f2bf(e0 * e[0][mf][i] + e1 * e[1][mf][i] + e2 * e[2][mf][i]);
                *(ushort4v*)(enh + orow + (size_t)(nl + nf * 16) * 32 + cob) = o;
            }
        }
    }
}

// ============ weight prepack (fragment order) =============================
__global__ void prepack_k(
    const float* __restrict__ f4w, const float* __restrict__ e1w,
    const float* __restrict__ e2w, const float* __restrict__ e3w,
    const float* __restrict__ f1w, const float* __restrict__ f2w,
    const float* __restrict__ f3w, const float* __restrict__ p1w,
    const float* __restrict__ p2w, const float* __restrict__ p3w,
    u16* __restrict__ apack)
{
    int gid = blockIdx.x * 256 + threadIdx.x;
    if (gid >= 77 * 1024) return;
    const int offs[11] = {0, 18, 27, 36, 45, 54, 63, 72, 73, 75, 77};
    int step = gid >> 10, r = gid & 1023;
    int layer = 0;
    while (step >= offs[layer + 1]) layer++;
    int s = step - offs[layer];
    int mf = r >> 9, l = (r >> 3) & 63, j = r & 7;
    int co = mf * 16 + (l & 15);
    int ICB = (layer == 0 || layer == 8 || layer == 9) ? 2 : 1;
    int tap = s / ICB, icb = s % ICB;
    int icl = icb * 32 + (l >> 4) * 8 + j;
    float v = 0.f;
    if (layer == 0)      { if (icl < 33) v = f4w[(co * 33 + icl) * 9 + tap]; }
    else if (layer == 1) v = e1w[(co * 32 + icl) * 9 + tap];
    else if (layer == 2) v = e2w[(co * 32 + icl) * 9 + tap];
    else if (layer == 3) v = e3w[(co * 32 + icl) * 9 + tap];
    else if (layer == 4) v = f1w[(co * 32 + icl) * 9 + tap];
    else if (layer == 5) v = f2w[(co * 32 + icl) * 9 + tap];
    else if (layer == 6) v = f3w[(co * 32 + icl) * 9 + tap];
    else if (layer == 7) v = p1w[co * 32 + icl];
    else if (layer == 8) v = p2w[co * 64 + icl];
    else                 v = p3w[co * 64 + icl];
    apack[gid] = f2bf(v);
}

// ============ composed-weight prep (LDS-staged): w5[32][25], be[32] =======
__global__ __launch_bounds__(256) void prep5_k(
    const float* __restrict__ f4w, const float* __restrict__ f4b,
    const float* __restrict__ sbase, const float* __restrict__ sfac,
    const float* __restrict__ sbias,
    float* __restrict__ w5, float* __restrict__ be)
{
    __shared__ float sF[32 * 33 * 9];
    __shared__ float sS[288];
    __shared__ float sBias[32];
    int t = threadIdx.x;
    for (int i = t; i < 32 * 33 * 9; i += 256) sF[i] = f4w[i];
    for (int i = t; i < 288; i += 256) sS[i] = sbase[i] * sfac[i / 9];
    if (t < 32) sBias[t] = sbias[t];
    __syncthreads();

    for (int idx = t; idx < 800; idx += 256) {
        int co = idx / 25, tap = idx % 25, kh = tap / 5, kw = tap % 5;
        float s = 0.f;
        if (kh >= 1 && kh <= 3 && kw >= 1 && kw <= 3)
            s = sF[(co * 33 + 0) * 9 + (kh - 1) * 3 + (kw - 1)];
        for (int sc = 0; sc < 32; ++sc) {
            #pragma unroll
            for (int a = 0; a < 3; ++a)
                #pragma unroll
                for (int bq = 0; bq < 3; ++bq) {
                    int p = kh - a, q = kw - bq;
                    if (p >= 0 && p < 3 && q >= 0 && q < 3)
                        s = fmaf(sF[(co * 33 + 1 + sc) * 9 + a * 3 + bq],
                                 sS[sc * 9 + p * 3 + q], s);
                }
        }
        w5[idx] = s;
    }
    for (int co = t; co < 32; co += 256) {
        float s = f4b[co];
        for (int sc = 0; sc < 32; ++sc) {
            float wsum = 0.f;
            #pragma unroll
            for (int k = 0; k < 9; ++k) wsum += sF[(co * 33 + 1 + sc) * 9 + k];
            s = fmaf(sBias[sc], wsum, s);
        }
        be[co] = s;
    }
}

// ============ composed 5x5 conv on x -> out1 (+ zero pad cols) ============
__global__ __launch_bounds__(256) void conv5_k(
    const float* __restrict__ x, const float* __restrict__ w5,
    const float* __restrict__ be, u16* __restrict__ out1)
{
    __shared__ float sw[800];
    __shared__ float sb[32];
    int tid = threadIdx.x;
    for (int i = tid; i < 800; i += 256) sw[i] = w5[i];
    if (tid < 32) sb[tid] = be[tid];
    __syncthreads();
    int b = blockIdx.x & 7, h = blockIdx.x >> 3, w = tid;
    const float* xp = x + (size_t)b * 65536;
    float xv[25];
    #pragma unroll
    for (int i = 0; i < 5; ++i) {
        int r = h + i - 2;
        #pragma unroll
        for (int j = 0; j < 5; ++j) {
            int c = w + j - 2;
            xv[i * 5 + j] = ((unsigned)r < 256u && (unsigned)c < 256u)
                            ? xp[r * 256 + c] : 0.f;
        }
    }
    u16* dst = out1 + ((size_t)b * HPW + (size_t)h * PW + PAD + w) * 32;
    #pragma unroll
    for (int cb = 0; cb < 4; ++cb) {
        short8 o;
        #pragma unroll
        for (int j = 0; j < 8; ++j) {
            int co = cb * 8 + j;
            float s = sb[co];
            #pragma unroll
            for (int t2 = 0; t2 < 25; ++t2) s = fmaf(sw[co * 25 + t2], xv[t2], s);
            s = (s > 0.f) ? s : 0.01f * s;
            o[j] = (short)f2bf(s);
        }
        *(short8*)(dst + cb * 8) = o;
    }
    if (tid < 24) {
        int col6 = tid >> 2, chunk = tid & 3;
        int col = (col6 < 3) ? col6 : (256 + PAD + col6 - 3);
        u16* pz = out1 + ((size_t)b * HPW + (size_t)h * PW + col) * 32 + chunk * 8;
        *(short8*)pz = (short8){0, 0, 0, 0, 0, 0, 0, 0};
    }
}

// ============ exact recompute of the 1-px ring ============================
__global__ __launch_bounds__(256) void ringfix_k(
    const float* __restrict__ x, const float* __restrict__ f4w,
    const float* __restrict__ f4b, const float* __restrict__ sbase,
    const float* __restrict__ sfac, const float* __restrict__ sbias,
    u16* __restrict__ out1)
{
    __shared__ float sW[288];
    __shared__ float sB[32];
    __shared__ float sF[32 * 33 * 9];
    __shared__ float sO[66][2][32];
    int tid = threadIdx.x;
    for (int i = tid; i < 288; i += 256) sW[i] = sbase[i] * sfac[i / 9];
    if (tid < 32) sB[tid] = sbias[tid];
    for (int i = tid; i < 32 * 33 * 9; i += 256) sF[i] = f4w[i];
    __syncthreads();

    int blk = blockIdx.x;
    int b = blk & 7, rest = blk >> 3;
    int e = rest >> 2, seg = rest & 3;
    const float* xp = x + (size_t)b * 65536;

    for (int i = tid; i < 66 * 2 * 32; i += 256) {
        int sc = i & 31, rr2 = i >> 5;
        int d = rr2 & 1, ul = rr2 >> 1;
        int ug = seg * 64 - 1 + ul;
        float v = 0.f;
        if ((unsigned)ug < 256u) {
            int h, w;
            if (e == 0)      { h = d;        w = ug; }
            else if (e == 1) { h = 255 - d;  w = ug; }
            else if (e == 2) { h = ug;       w = d; }
            else             { h = ug;       w = 255 - d; }
            float s = sB[sc];
            for (int p = 0; p < 3; ++p)
                for (int q = 0; q < 3; ++q) {
                    int rr = h + p - 1, cc = w + q - 1;
                    if ((unsigned)rr < 256u && (unsigned)cc < 256u)
                        s = fmaf(sW[sc * 9 + p * 3 + q], xp[rr * 256 + cc], s);
                }
            v = s;
        }
        sO[ul][d][sc] = v;
    }
    __syncthreads();

    int pi = tid & 63, cog = tid >> 6;
    int up = seg * 64 + pi;
    int h, w;
    if (e == 0)      { h = 0;   w = up; }
    else if (e == 1) { h = 255; w = up; }
    else if (e == 2) { h = up;  w = 0; }
    else             { h = up;  w = 255; }
    short8 ov;
    for (int cj = 0; cj < 8; ++cj) {
        int co = cog * 8 + cj;
        float acc = f4b[co];
        for (int a = 0; a < 3; ++a)
            for (int bb = 0; bb < 3; ++bb) {
                int hh = h + a - 1, ww = w + bb - 1;
                if ((unsigned)hh < 256u && (unsigned)ww < 256u)
                    acc = fmaf(sF[(co * 33) * 9 + a * 3 + bb], xp[hh * 256 + ww], acc);
                int d, ug;
                if (e == 0)      { d = hh;        ug = ww; }
                else if (e == 1) { d = 255 - hh;  ug = ww; }
                else if (e == 2) { d = ww;        ug = hh; }
                else             { d = 255 - ww;  ug = hh; }
                if (d >= 0 && d < 2 && (unsigned)ug < 256u) {
                    int ul = ug - (seg * 64 - 1);
                    for (int sc = 0; sc < 32; ++sc)
                        acc = fmaf(sF[(co * 33 + 1 + sc) * 9 + a * 3 + bb], sO[ul][d][sc], acc);
                }
            }
        acc = (acc > 0.f) ? acc : 0.01f * acc;
        ov[cj] = (short)f2bf(acc);
    }
    u16* dst = out1 + ((size_t)b * HPW + (size_t)h * PW + PAD + w) * 32 + cog * 8;
    *(short8*)dst = ov;
}

// ============ channel attention ===========================================
__global__ __launch_bounds__(256) void ca_part_k(
    const u16* __restrict__ enh, float* __restrict__ part)
{
    int blk = blockIdx.x, b = blk & 7, sl = blk >> 3;
    int tid = threadIdx.x, lane = tid & 63, wv = tid >> 6;
    float s[32], m[32];
    #pragma unroll
    for (int c = 0; c < 32; ++c) { s[c] = 0.f; m[c] = -1e30f; }
    for (int k = 0; k < 8; ++k) {
        int px = sl * 2048 + k * 256 + tid;
        int h = px >> 8, w = px & 255;
        size_t off = ((size_t)b * HPW + (size_t)h * PW + PAD + w) * 32;
        #pragma unroll
        for (int cb = 0; cb < 4; ++cb) {
            short8 v = *(const short8*)(enh + off + cb * 8);
            #pragma unroll
            for (int j = 0; j < 8; ++j) {
                float f = bf2f((u16)v[j]);
                s[cb * 8 + j] += f;
                m[cb * 8 + j] = fmaxf(m[cb * 8 + j], f);
            }
        }
    }
    #pragma unroll
    for (int c = 0; c < 32; ++c)
        #pragma unroll
        for (int o = 32; o; o >>= 1) {
            s[c] += __shfl_down(s[c], o);
            m[c] = fmaxf(m[c], __shfl_down(m[c], o));
        }
    __shared__ float ls[4][32], lm[4][32];
    if (lane == 0)
        for (int c = 0; c < 32; ++c) { ls[wv][c] = s[c]; lm[wv][c] = m[c]; }
    __syncthreads();
    if (tid < 32) {
        float ts = 0.f, tm = -1e30f;
        for (int w2 = 0; w2 < 4; ++w2) { ts += ls[w2][tid]; tm = fmaxf(tm, lm[w2][tid]); }
        int bs = b * 32 + sl;
        part[(size_t)(bs * 2 + 0) * 32 + tid] = ts;
        part[(size_t)(bs * 2 + 1) * 32 + tid] = tm;
    }
}

__global__ void ca_final_k(const float* __restrict__ part,
                           const float* __restrict__ w1, const float* __restrict__ w2,
                           float* __restrict__ ca)
{
    int t = threadIdx.x, b = t >> 5, c = t & 31;
    float s = 0.f, m = -1e30f;
    for (int sl = 0; sl < 32; ++sl) {
        int bs = b * 32 + sl;
        s += part[(size_t)(bs * 2 + 0) * 32 + c];
        m = fmaxf(m, part[(size_t)(bs * 2 + 1) * 32 + c]);
    }
    __shared__ float av[8][32], mx[8][32];
    av[b][c] = s * (1.f / 65536.f);
    mx[b][c] = m;
    __syncthreads();
    float sa0 = 0.f, sm0 = 0.f, sa1 = 0.f, sm1 = 0.f;
    for (int k = 0; k < 32; ++k) {
        float wa = w1[k], wb = w1[32 + k];
        sa0 = fmaf(wa, av[b][k], sa0); sm0 = fmaf(wa, mx[b][k], sm0);
        sa1 = fmaf(wb, av[b][k], sa1); sm1 = fmaf(wb, mx[b][k], sm1);
    }
    float h0 = fmaxf(sa0, 0.f) + fmaxf(sm0, 0.f);
    float h1 = fmaxf(sa1, 0.f) + fmaxf(sm1, 0.f);
    ca[t] = sigm(w2[c * 2 + 0] * h0 + w2[c * 2 + 1] * h1);
}

// ============ SA input maps (padded 262x262) ==============================
__global__ __launch_bounds__(256) void samap_k(
    const u16* __restrict__ enh, const float* __restrict__ ca,
    float* __restrict__ smap)
{
    __shared__ float sca[256];
    int tid = threadIdx.x;
    sca[tid] = ca[tid];
    __syncthreads();
    int b = blockIdx.x & 7;
    int r = (blockIdx.x >> 3) * 256 + tid;
    if (r >= 262 * 262) return;
    int ph = r / 262, pw = r % 262;
    float mean = 0.f, mxv = 0.f;
    if (ph >= 3 && ph < 259 && pw >= 3 && pw < 259) {
        int h = ph - 3, w = pw - 3;
        size_t off = ((size_t)b * HPW + (size_t)h * PW + PAD + w) * 32;
        float s = 0.f, m = -1e30f;
        #pragma unroll
        for (int cb = 0; cb < 4; ++cb) {
            short8 v = *(const short8*)(enh + off + cb * 8);
            #pragma unroll
            for (int j = 0; j < 8; ++j) {
                float f = bf2f((u16)v[j]) * sca[b * 32 + cb * 8 + j];
                s += f; m = fmaxf(m, f);
            }
        }
        mean = s * (1.f / 32.f); mxv = m;
    }
    smap[((size_t)b * 262 * 262 + (size_t)ph * 262 + pw) * 2 + 0] = mean;
    smap[((size_t)b * 262 * 262 + (size_t)ph * 262 + pw) * 2 + 1] = mxv;
}

// ============ 7x7 SA conv + merge + fused p1 (1x1 via MFMA) ===============
__global__ __launch_bounds__(256) void merge_k(
    const float* __restrict__ smap, const float* __restrict__ saw,
    const float* __restrict__ ca, const u16* __restrict__ out1,
    const u16* __restrict__ enh, u16* __restrict__ o0,
    float* __restrict__ dout,
    const u16* __restrict__ ap1, const float* __restrict__ p1b,
    u16* __restrict__ p1out)
{
    __shared__ float sw[98];
    __shared__ float sca[256];
    __shared__ u16 tile[256 * 32];   // out0 bf16 tile, 16 KB
    int tid = threadIdx.x;
    for (int i = tid; i < 98; i += 256) sw[i] = saw[i];
    sca[tid] = ca[tid];
    __syncthreads();
    int b = blockIdx.x & 7;
    int h = blockIdx.x >> 3;
    int w = tid;
    const float* sp = smap + (size_t)b * 262 * 262 * 2;
    float acc = 0.f;
    #pragma unroll
    for (int kh = 0; kh < 7; ++kh)
        #pragma unroll
        for (int kw = 0; kw < 7; ++kw) {
            const float* q = sp + ((size_t)(h + kh) * 262 + (w + kw)) * 2;
            acc = fmaf(q[0], sw[kh * 7 + kw], acc);
            acc = fmaf(q[1], sw[49 + kh * 7 + kw], acc);
        }
    float sa = sigm(acc);
    size_t off = ((size_t)b * HPW + (size_t)h * PW + PAD + w) * 32;
    float* dp = dout + (size_t)b * 64 * 65536 + (size_t)h * 256 + w;
    #pragma unroll
    for (int cb = 0; cb < 4; ++cb) {
        short8 ve = *(const short8*)(enh + off + cb * 8);
        short8 vo = *(const short8*)(out1 + off + cb * 8);
        short8 o;
        #pragma unroll
        for (int j = 0; j < 8; ++j) {
            float f = sca[b * 32 + cb * 8 + j] * bf2f((u16)ve[j]);
            float v = bf2f((u16)vo[j]) + sa * f;
            v = (v > 0.f) ? v : 0.01f * v;
            o[j] = (short)f2bf(v);
            dp[(size_t)(cb * 8 + j) * 65536] = v;
        }
        *(short8*)(o0 + off + cb * 8) = o;
        *(short8*)(&tile[w * 32 + cb * 8]) = o;
    }
    __syncthreads();
    // fused p1: 1x1 over out0 tile, K=32 single step
    const int lane = tid & 63, wv = tid >> 6;
    const int icg = lane >> 4, l15 = lane & 15;
    f32x4 acc1[2][4];
    #pragma unroll
    for (int mf = 0; mf < 2; ++mf)
        #pragma unroll
        for (int nf = 0; nf < 4; ++nf)
            acc1[mf][nf] = (f32x4){0.f, 0.f, 0.f, 0.f};
    short8 pa0 = *(const short8*)(ap1 + (size_t)0 * 512 + lane * 8);
    short8 pa1 = *(const short8*)(ap1 + (size_t)1 * 512 + lane * 8);
    #pragma unroll
    for (int nf = 0; nf < 4; ++nf) {
        short8 bf = *(const short8*)(&tile[(wv * 64 + l15 + nf * 16) * 32 + icg * 8]);
        acc1[0][nf] = __builtin_amdgcn_mfma_f32_16x16x32_bf16(pa0, bf, acc1[0][nf], 0, 0, 0);
        acc1[1][nf] = __builtin_amdgcn_mfma_f32_16x16x32_bf16(pa1, bf, acc1[1][nf], 0, 0, 0);
    }
    const size_t orow = ((size_t)b * HPW + (size_t)h * PW + PAD) * 32;
    #pragma unroll
    for (int mf = 0; mf < 2; ++mf) {
        const int cob = mf * 16 + icg * 4;
        f32x4 pbi = *(const f32x4*)(p1b + cob);
        #pragma unroll
        for (int nf = 0; nf < 4; ++nf) {
            const int px = wv * 64 + l15 + nf * 16;
            ushort4v o;
            #pragma unroll
            for (int i = 0; i < 4; ++i) {
                float v = acc1[mf][nf][i] + pbi[i];
                v = (v > 0.f) ? v : 0.01f * v;
                o[i] = f2bf(v);
            }
            *(ushort4v*)(p1out + orow + (size_t)px * 32 + cob) = o;
        }
    }
}

extern "C" void kernel_launch(void* const* d_in, const int* in_sizes, int n_in,
                              void* d_out, int out_size, void* d_ws, size_t ws_size,
                              hipStream_t stream)
{
    (void)in_sizes; (void)n_in; (void)out_size; (void)ws_size;
    const float* x        = (const float*)d_in[0];
    const float* sob_base = (const float*)d_in[1];
    const float* sob_fac  = (const float*)d_in[2];
    const float* sob_bias = (const float*)d_in[3];
    const float* f4_w = (const float*)d_in[4];   const float* f4_b = (const float*)d_in[5];
    const float* ec1_w = (const float*)d_in[6];  const float* ec1_b = (const float*)d_in[7];
    const float* ec2_w = (const float*)d_in[8];  const float* ec2_b = (const float*)d_in[9];
    const float* ec3_w = (const float*)d_in[10]; const float* ec3_b = (const float*)d_in[11];
    const float* gate_w = (const float*)d_in[12]; const float* gate_b = (const float*)d_in[13];
    const float* ca1_w = (const float*)d_in[14]; const float* ca2_w = (const float*)d_in[15];
    const float* sa_w  = (const float*)d_in[16];
    const float* p1_w = (const float*)d_in[17]; const float* p1_b = (const float*)d_in[18];
    const float* f1_w = (const float*)d_in[19]; const float* f1_b = (const float*)d_in[20];
    const float* p2_w = (const float*)d_in[21]; const float* p2_b = (const float*)d_in[22];
    const float* f2_w = (const float*)d_in[23]; const float* f2_b = (const float*)d_in[24];
    const float* p3_w = (const float*)d_in[25]; const float* p3_b = (const float*)d_in[26];
    const float* f3_w = (const float*)d_in[27]; const float* f3_b = (const float*)d_in[28];

    const size_t PB32 = (size_t)Bb * HPW * 32 * 2;
    char* ws = (char*)d_ws;
    u16* Q    = (u16*)(ws);
    u16* O0   = (u16*)(ws + PB32);
    u16* T    = (u16*)(ws + 2 * PB32);
    u16* ENH  = (u16*)(ws + 3 * PB32);
    u16* AP   = (u16*)(ws + 4 * PB32);
    float* W5   = (float*)(ws + 4 * PB32 + 77 * 1024 * 2);
    float* BE   = W5 + 800;
    float* PART = BE + 32;
    float* CA   = PART + 8 * 32 * 2 * 32;

    char* doutc = (char*)d_out;
    float* SMAP = (float*)(doutc + (134217728 - (size_t)Bb * 262 * 262 * 2 * 4));
    float* dout = (float*)d_out;

    dim3 blk(256);

    prepack_k<<<308, blk, 0, stream>>>(f4_w, ec1_w, ec2_w, ec3_w, f1_w, f2_w, f3_w,
                                       p1_w, p2_w, p3_w, AP);
    prep5_k<<<1, blk, 0, stream>>>(f4_w, f4_b, sob_base, sob_fac, sob_bias, W5, BE);
    conv5_k<<<2048, blk, 0, stream>>>(x, W5, BE, Q);
    ringfix_k<<<128, blk, 0, stream>>>(x, f4_w, f4_b, sob_base, sob_fac, sob_bias, Q);
    // fused ec1/ec2/ec3 + gate + blend -> ENH (2 rows/block)
    ecfuse_k<<<2048, blk, 0, stream>>>(Q, AP + 18 * 1024, ec1_b, ec2_b, ec3_b,
                                       gate_w, gate_b, ENH);
    ca_part_k<<<256, blk, 0, stream>>>(ENH, PART);
    ca_final_k<<<1, blk, 0, stream>>>(PART, ca1_w, ca2_w, CA);
    samap_k<<<2152, blk, 0, stream>>>(ENH, CA, SMAP);
    merge_k<<<2048, blk, 0, stream>>>(SMAP, sa_w, CA, Q, ENH, O0, dout,
                                      AP + 72 * 1024, p1_b, Q);
    convs_k<2, false, true ><<<2048, blk, 0, stream>>>(Q, AP + 45 * 1024, f1_b, nullptr,
                                                       O0, AP + 73 * 1024, p2_b, T);
    convs_k<2, false, true ><<<2048, blk, 0, stream>>>(T, AP + 54 * 1024, f2_b, nullptr,
                                                       O0, AP + 75 * 1024, p3_b, Q);
    convs_k<2, true, false><<<2048, blk, 0, stream>>>(Q, AP + 63 * 1024, f3_b, dout,
                                                      nullptr, nullptr, nullptr, nullptr);
}

// Round 23
// 385.998 us; speedup vs baseline: 1.1297x; 1.1297x over previous
//
#include <hip/hip_runtime.h>
#include <math.h>

typedef unsigned short u16;
typedef short short8 __attribute__((ext_vector_type(8)));
typedef float f32x4 __attribute__((ext_vector_type(4)));
typedef unsigned short ushort4v __attribute__((ext_vector_type(4)));

#define Hh 256
#define Ww 256
#define Bb 8
#define PW 262
#define PAD 3
#define HPW (Hh * PW)

__device__ __forceinline__ float bf2f(u16 v) {
    unsigned u = ((unsigned)v) << 16;
    union { unsigned u; float f; } c; c.u = u; return c.f;
}
__device__ __forceinline__ u16 f2bf(float f) {
    union { float f; unsigned u; } c; c.f = f;
    unsigned lsb = (c.u >> 16) & 1u;
    c.u += 0x7fffu + lsb;
    return (u16)(c.u >> 16);
}
__device__ __forceinline__ float sigm(float v) { return 1.f / (1.f + expf(-v)); }

// ============ 3x3 conv, 2 rows/block, B staged in LDS (4 rows) ============
// FUSEP: f output (lrelu) -> LDS tile; 1x1 over concat(O0, tile) -> pout.
template<int ACT, bool F32OUT, bool FUSEP>
__global__ __launch_bounds__(256) void convs_k(
    const u16* __restrict__ in, const u16* __restrict__ apack,
    const float* __restrict__ bias, void* __restrict__ outp,
    const u16* __restrict__ o0buf, const u16* __restrict__ pw,
    const float* __restrict__ pb, u16* __restrict__ pout)
{
    __shared__ u16 rows[4][4352];   // 34816 B; rows[0..1] reused as f tile
    const int tid = threadIdx.x, lane = tid & 63, wv = tid >> 6;
    const int b = blockIdx.x & 7;
    const int rest = blockIdx.x >> 3;        // 0..255
    const int hpair = rest >> 1, half = rest & 1;
    const int h0 = hpair * 2;
    const int pl = wv * 32 + (lane & 15);
    const int icg = lane >> 4;

    for (int idx = tid; idx < 4 * 536; idx += 256) {
        int rr = idx / 536, q = idx % 536;
        int r = h0 - 1 + rr;
        short8 v = (short8){0, 0, 0, 0, 0, 0, 0, 0};
        if ((unsigned)r < 256u)
            v = *(const short8*)(in + ((size_t)b * HPW + (size_t)r * PW + PAD + half * 128 - 3) * 32
                                 + (size_t)q * 8);
        *(short8*)(&rows[rr][q * 8]) = v;
    }
    __syncthreads();

    f32x4 acc[2][2][2];   // [row][mf][nf]
    #pragma unroll
    for (int r2 = 0; r2 < 2; ++r2)
        #pragma unroll
        for (int mf = 0; mf < 2; ++mf)
            #pragma unroll
            for (int nf = 0; nf < 2; ++nf)
                acc[r2][mf][nf] = (f32x4){0.f, 0.f, 0.f, 0.f};

    #pragma unroll
    for (int tap = 0; tap < 9; ++tap) {
        const int kh = tap / 3 - 1, kw = tap % 3 - 1;
        short8 a0 = *(const short8*)(apack + ((size_t)(tap * 2 + 0) * 64 + lane) * 8);
        short8 a1 = *(const short8*)(apack + ((size_t)(tap * 2 + 1) * 64 + lane) * 8);
        #pragma unroll
        for (int r2 = 0; r2 < 2; ++r2) {
            const int ri = 1 + r2 + kh;   // 0..3
            #pragma unroll
            for (int nf = 0; nf < 2; ++nf) {
                short8 bf = *(const short8*)(&rows[ri][(pl + nf * 16 + kw + 3) * 32 + icg * 8]);
                acc[r2][0][nf] = __builtin_amdgcn_mfma_f32_16x16x32_bf16(a0, bf, acc[r2][0][nf], 0, 0, 0);
                acc[r2][1][nf] = __builtin_amdgcn_mfma_f32_16x16x32_bf16(a1, bf, acc[r2][1][nf], 0, 0, 0);
            }
        }
    }
    const int nl = half * 128 + pl;
    f32x4 bi[2];
    bi[0] = *(const f32x4*)(bias + icg * 4);
    bi[1] = *(const f32x4*)(bias + 16 + icg * 4);

    if (FUSEP) {
        u16* tile = &rows[0][0];
        __syncthreads();
        #pragma unroll
        for (int r2 = 0; r2 < 2; ++r2)
            #pragma unroll
            for (int mf = 0; mf < 2; ++mf) {
                const int cob = mf * 16 + icg * 4;
                #pragma unroll
                for (int nf = 0; nf < 2; ++nf) {
                    ushort4v o;
                    #pragma unroll
                    for (int i = 0; i < 4; ++i) {
                        float v = acc[r2][mf][nf][i] + bi[mf][i];
                        v = (v > 0.f) ? v : 0.01f * v;
                        o[i] = f2bf(v);
                    }
                    *(ushort4v*)(tile + ((size_t)(r2 * 128 + pl + nf * 16)) * 32 + cob) = o;
                }
            }
        __syncthreads();
        #pragma unroll
        for (int r2 = 0; r2 < 2; ++r2) {
            const int h = h0 + r2;
            f32x4 acc2[2][2];
            #pragma unroll
            for (int mf = 0; mf < 2; ++mf)
                #pragma unroll
                for (int nf = 0; nf < 2; ++nf)
                    acc2[mf][nf] = (f32x4){0.f, 0.f, 0.f, 0.f};
            #pragma unroll
            for (int s = 0; s < 2; ++s) {
                short8 pa0 = *(const short8*)(pw + (size_t)(s * 2 + 0) * 512 + lane * 8);
                short8 pa1 = *(const short8*)(pw + (size_t)(s * 2 + 1) * 512 + lane * 8);
                #pragma unroll
                for (int nf = 0; nf < 2; ++nf) {
                    const int px = pl + nf * 16;
                    short8 bf;
                    if (s == 0)
                        bf = *(const short8*)(o0buf + ((size_t)b * HPW + (size_t)h * PW + PAD + half * 128 + px) * 32 + icg * 8);
                    else
                        bf = *(const short8*)(tile + ((size_t)(r2 * 128 + px)) * 32 + icg * 8);
                    acc2[0][nf] = __builtin_amdgcn_mfma_f32_16x16x32_bf16(pa0, bf, acc2[0][nf], 0, 0, 0);
                    acc2[1][nf] = __builtin_amdgcn_mfma_f32_16x16x32_bf16(pa1, bf, acc2[1][nf], 0, 0, 0);
                }
            }
            const size_t orow = ((size_t)b * HPW + (size_t)h * PW + PAD) * 32;
            #pragma unroll
            for (int mf = 0; mf < 2; ++mf) {
                const int cob = mf * 16 + icg * 4;
                f32x4 pbi = *(const f32x4*)(pb + cob);
                #pragma unroll
                for (int nf = 0; nf < 2; ++nf) {
                    ushort4v o;
                    #pragma unroll
                    for (int i = 0; i < 4; ++i) {
                        float v = acc2[mf][nf][i] + pbi[i];
                        v = (v > 0.f) ? v : 0.01f * v;
                        o[i] = f2bf(v);
                    }
                    *(ushort4v*)(pout + orow + (size_t)(nl + nf * 16) * 32 + cob) = o;
                }
            }
        }
        if (tid < 24) {
            int r2 = tid / 12, rem = tid % 12;
            int col3 = rem >> 2, chunk = rem & 3;
            int col = half ? (256 + PAD + col3) : col3;
            u16* pz = pout + ((size_t)b * HPW + (size_t)(h0 + r2) * PW + col) * 32 + chunk * 8;
            *(short8*)pz = (short8){0, 0, 0, 0, 0, 0, 0, 0};
        }
    } else if (F32OUT) {
        #pragma unroll
        for (int r2 = 0; r2 < 2; ++r2) {
            float* dp = (float*)outp + ((size_t)b * 64 + 32) * 65536 + (size_t)(h0 + r2) * 256;
            #pragma unroll
            for (int mf = 0; mf < 2; ++mf) {
                const int cob = mf * 16 + icg * 4;
                #pragma unroll
                for (int nf = 0; nf < 2; ++nf) {
                    const int w = nl + nf * 16;
                    #pragma unroll
                    for (int i = 0; i < 4; ++i) {
                        float v = acc[r2][mf][nf][i] + bi[mf][i];
                        if (ACT == 1) v = fmaxf(v, 0.f);
                        if (ACT == 2) v = (v > 0.f) ? v : 0.01f * v;
                        dp[(size_t)(cob + i) * 65536 + w] = v;
                    }
                }
            }
        }
    } else {
        u16* out = (u16*)outp;
        #pragma unroll
        for (int r2 = 0; r2 < 2; ++r2) {
            const size_t orow = ((size_t)b * HPW + (size_t)(h0 + r2) * PW + PAD) * 32;
            #pragma unroll
            for (int mf = 0; mf < 2; ++mf) {
                const int cob = mf * 16 + icg * 4;
                #pragma unroll
                for (int nf = 0; nf < 2; ++nf) {
                    ushort4v o;
                    #pragma unroll
                    for (int i = 0; i < 4; ++i) {
                        float v = acc[r2][mf][nf][i] + bi[mf][i];
                        if (ACT == 1) v = fmaxf(v, 0.f);
                        if (ACT == 2) v = (v > 0.f) ? v : 0.01f * v;
                        o[i] = f2bf(v);
                    }
                    *(ushort4v*)(out + orow + (size_t)(nl + nf * 16) * 32 + cob) = o;
                }
            }
        }
    }
}

// ============ fused ec1/ec2/ec3 + gate, shared-center + halo dbuf =========
// Center row h staged ONCE; per-phase +-dil halo rows double-buffered with
// register-staged prefetch (latency hidden under MFMA taps).
__global__ __launch_bounds__(256) void ecfuse_k(
    const u16* __restrict__ in, const u16* __restrict__ apack,
    const float* __restrict__ b1, const float* __restrict__ b2,
    const float* __restrict__ b3, const float* __restrict__ gw_,
    const float* __restrict__ gb_, u16* __restrict__ enh)
{
    __shared__ u16 crow[4288];          // center row h (134px x 32ch)
    __shared__ u16 halo[2][2][4288];    // [buf][lo/hi]
    __shared__ float gw[288];
    __shared__ float gb[3];
    __shared__ float bs[96];
    int tid = threadIdx.x;
    for (int i = tid; i < 288; i += 256) gw[i] = gw_[i];
    if (tid < 3) gb[tid] = gb_[tid];
    if (tid < 32) bs[tid] = b1[tid];
    else if (tid < 64) bs[tid] = b2[tid - 32];
    else if (tid < 96) bs[tid] = b3[tid - 64];

    const int lane = tid & 63, wv = tid >> 6;
    const int b = blockIdx.x & 7;
    const int rest = blockIdx.x >> 3;
    const int h = rest >> 1, half = rest & 1;
    const int pl = wv * 32 + (lane & 15);
    const int icg = lane >> 4;
    const u16* src_base = in + ((size_t)b * HPW + PAD + half * 128 - 3) * 32;

    // initial staging: center + dil=1 halos (rr: 0 -> h-1, 1 -> h, 2 -> h+1)
    for (int idx = tid; idx < 1608; idx += 256) {
        int rr = idx / 536, q = idx % 536;
        int r = h + (rr - 1);
        short8 v = (short8){0, 0, 0, 0, 0, 0, 0, 0};
        if ((unsigned)r < 256u)
            v = *(const short8*)(src_base + (size_t)r * PW * 32 + (size_t)q * 8);
        u16* dst = (rr == 1) ? &crow[q * 8] : &halo[0][rr >> 1][q * 8];
        *(short8*)dst = v;
    }
    __syncthreads();

    f32x4 acc[3][2][2];
    #pragma unroll
    for (int cv = 0; cv < 3; ++cv)
        #pragma unroll
        for (int mf = 0; mf < 2; ++mf)
            #pragma unroll
            for (int nf = 0; nf < 2; ++nf)
                acc[cv][mf][nf] = (f32x4){0.f, 0.f, 0.f, 0.f};

    #pragma unroll
    for (int cv = 0; cv < 3; ++cv) {
        const int dil = cv + 1;
        const int nb = cv & 1;
        // prefetch next phase's 2 halo rows into registers (4 chunks)
        short8 stg0, stg1, stg2, stg3;
        if (cv < 2) {
            const int dn = cv + 2;
            #pragma unroll
            for (int k = 0; k < 4; ++k) {
                int idx = tid + k * 256;            // < 1024 (of 1072)
                int rr = idx / 536, q = idx % 536;
                int r = h + (rr ? dn : -dn);
                short8 v = (short8){0, 0, 0, 0, 0, 0, 0, 0};
                if ((unsigned)r < 256u)
                    v = *(const short8*)(src_base + (size_t)r * PW * 32 + (size_t)q * 8);
                if (k == 0) stg0 = v; else if (k == 1) stg1 = v;
                else if (k == 2) stg2 = v; else stg3 = v;
            }
        }
        // compute phase cv: kh=-1 -> halo[nb][0], kh=0 -> crow, kh=+1 -> halo[nb][1]
        const u16* ap = apack + (size_t)(cv * 9 * 2) * 512;
        #pragma unroll
        for (int tap = 0; tap < 9; ++tap) {
            const int kh = tap / 3 - 1, kw = tap % 3 - 1;
            const u16* rp = (kh == -1) ? &halo[nb][0][0]
                          : (kh == 0) ? &crow[0] : &halo[nb][1][0];
            short8 a0 = *(const short8*)(ap + (size_t)(tap * 2 + 0) * 512 + lane * 8);
            short8 a1 = *(const short8*)(ap + (size_t)(tap * 2 + 1) * 512 + lane * 8);
            #pragma unroll
            for (int nf = 0; nf < 2; ++nf) {
                short8 bf = *(const short8*)(rp + (pl + nf * 16 + kw * dil + 3) * 32 + icg * 8);
                acc[cv][0][nf] = __builtin_amdgcn_mfma_f32_16x16x32_bf16(a0, bf, acc[cv][0][nf], 0, 0, 0);
                acc[cv][1][nf] = __builtin_amdgcn_mfma_f32_16x16x32_bf16(a1, bf, acc[cv][1][nf], 0, 0, 0);
            }
        }
        // write staged halos to the other buffer (+ tail for tid<48)
        if (cv < 2) {
            const int dn = cv + 2;
            #pragma unroll
            for (int k = 0; k < 4; ++k) {
                int idx = tid + k * 256;
                int rr = idx / 536, q = idx % 536;
                short8 v = (k == 0) ? stg0 : (k == 1) ? stg1 : (k == 2) ? stg2 : stg3;
                *(short8*)(&halo[1 - nb][rr][q * 8]) = v;
            }
            if (tid < 48) {
                int idx = tid + 1024;               // rr = 1, q = 488..535
                int q = idx % 536;
                int r = h + dn;
                short8 v = (short8){0, 0, 0, 0, 0, 0, 0, 0};
                if ((unsigned)r < 256u)
                    v = *(const short8*)(src_base + (size_t)r * PW * 32 + (size_t)q * 8);
                *(short8*)(&halo[1 - nb][1][q * 8]) = v;
            }
            __syncthreads();
        }
    }
    const int nl = half * 128 + pl;
    const size_t orow = ((size_t)b * HPW + (size_t)h * PW + PAD) * 32;
    #pragma unroll
    for (int nf = 0; nf < 2; ++nf) {
        float e[3][2][4];
        float g0 = 0.f, g1 = 0.f, g2 = 0.f;
        #pragma unroll
        for (int cv = 0; cv < 3; ++cv)
            #pragma unroll
            for (int mf = 0; mf < 2; ++mf) {
                const int cob = mf * 16 + icg * 4;
                #pragma unroll
                for (int i = 0; i < 4; ++i) {
                    float v = fmaxf(acc[cv][mf][nf][i] + bs[cv * 32 + cob + i], 0.f);
                    e[cv][mf][i] = v;
                    const int c = cv * 32 + cob + i;
                    g0 = fmaf(gw[c], v, g0);
                    g1 = fmaf(gw[96 + c], v, g1);
                    g2 = fmaf(gw[192 + c], v, g2);
                }
            }
        g0 += __shfl_xor(g0, 16); g0 += __shfl_xor(g0, 32);
        g1 += __shfl_xor(g1, 16); g1 += __shfl_xor(g1, 32);
        g2 += __shfl_xor(g2, 16); g2 += __shfl_xor(g2, 32);
        g0 += gb[0]; g1 += gb[1]; g2 += gb[2];
        float m = fmaxf(g0, fmaxf(g1, g2));
        float e0 = expf(g0 - m), e1 = expf(g1 - m), e2 = expf(g2 - m);
        float inv = 1.f / (e0 + e1 + e2);
        e0 *= inv; e1 *= inv; e2 *= inv;
        #pragma unroll
        for (int mf = 0; mf < 2; ++mf) {
            const int cob = mf * 16 + icg * 4;
            ushort4v o;
            #pragma unroll
            for (int i = 0; i < 4; ++i)
                o[i] = f2bf(e0 * e[0][mf][i] + e1 * e[1][mf][i] + e2 * e[2][mf][i]);
            *(ushort4v*)(enh + orow + (size_t)(nl + nf * 16) * 32 + cob) = o;
        }
    }
}

// ============ weight prepack (fragment order) =============================
__global__ void prepack_k(
    const float* __restrict__ f4w, const float* __restrict__ e1w,
    const float* __restrict__ e2w, const float* __restrict__ e3w,
    const float* __restrict__ f1w, const float* __restrict__ f2w,
    const float* __restrict__ f3w, const float* __restrict__ p1w,
    const float* __restrict__ p2w, const float* __restrict__ p3w,
    u16* __restrict__ apack)
{
    int gid = blockIdx.x * 256 + threadIdx.x;
    if (gid >= 77 * 1024) return;
    const int offs[11] = {0, 18, 27, 36, 45, 54, 63, 72, 73, 75, 77};
    int step = gid >> 10, r = gid & 1023;
    int layer = 0;
    while (step >= offs[layer + 1]) layer++;
    int s = step - offs[layer];
    int mf = r >> 9, l = (r >> 3) & 63, j = r & 7;
    int co = mf * 16 + (l & 15);
    int ICB = (layer == 0 || layer == 8 || layer == 9) ? 2 : 1;
    int tap = s / ICB, icb = s % ICB;
    int icl = icb * 32 + (l >> 4) * 8 + j;
    float v = 0.f;
    if (layer == 0)      { if (icl < 33) v = f4w[(co * 33 + icl) * 9 + tap]; }
    else if (layer == 1) v = e1w[(co * 32 + icl) * 9 + tap];
    else if (layer == 2) v = e2w[(co * 32 + icl) * 9 + tap];
    else if (layer == 3) v = e3w[(co * 32 + icl) * 9 + tap];
    else if (layer == 4) v = f1w[(co * 32 + icl) * 9 + tap];
    else if (layer == 5) v = f2w[(co * 32 + icl) * 9 + tap];
    else if (layer == 6) v = f3w[(co * 32 + icl) * 9 + tap];
    else if (layer == 7) v = p1w[co * 32 + icl];
    else if (layer == 8) v = p2w[co * 64 + icl];
    else                 v = p3w[co * 64 + icl];
    apack[gid] = f2bf(v);
}

// ============ composed-weight prep (LDS-staged): w5[32][25], be[32] =======
__global__ __launch_bounds__(256) void prep5_k(
    const float* __restrict__ f4w, const float* __restrict__ f4b,
    const float* __restrict__ sbase, const float* __restrict__ sfac,
    const float* __restrict__ sbias,
    float* __restrict__ w5, float* __restrict__ be)
{
    __shared__ float sF[32 * 33 * 9];
    __shared__ float sS[288];
    __shared__ float sBias[32];
    int t = threadIdx.x;
    for (int i = t; i < 32 * 33 * 9; i += 256) sF[i] = f4w[i];
    for (int i = t; i < 288; i += 256) sS[i] = sbase[i] * sfac[i / 9];
    if (t < 32) sBias[t] = sbias[t];
    __syncthreads();

    for (int idx = t; idx < 800; idx += 256) {
        int co = idx / 25, tap = idx % 25, kh = tap / 5, kw = tap % 5;
        float s = 0.f;
        if (kh >= 1 && kh <= 3 && kw >= 1 && kw <= 3)
            s = sF[(co * 33 + 0) * 9 + (kh - 1) * 3 + (kw - 1)];
        for (int sc = 0; sc < 32; ++sc) {
            #pragma unroll
            for (int a = 0; a < 3; ++a)
                #pragma unroll
                for (int bq = 0; bq < 3; ++bq) {
                    int p = kh - a, q = kw - bq;
                    if (p >= 0 && p < 3 && q >= 0 && q < 3)
                        s = fmaf(sF[(co * 33 + 1 + sc) * 9 + a * 3 + bq],
                                 sS[sc * 9 + p * 3 + q], s);
                }
        }
        w5[idx] = s;
    }
    for (int co = t; co < 32; co += 256) {
        float s = f4b[co];
        for (int sc = 0; sc < 32; ++sc) {
            float wsum = 0.f;
            #pragma unroll
            for (int k = 0; k < 9; ++k) wsum += sF[(co * 33 + 1 + sc) * 9 + k];
            s = fmaf(sBias[sc], wsum, s);
        }
        be[co] = s;
    }
}

// ============ composed 5x5 conv on x -> out1 (+ zero pad cols) ============
__global__ __launch_bounds__(256) void conv5_k(
    const float* __restrict__ x, const float* __restrict__ w5,
    const float* __restrict__ be, u16* __restrict__ out1)
{
    __shared__ float sw[800];
    __shared__ float sb[32];
    int tid = threadIdx.x;
    for (int i = tid; i < 800; i += 256) sw[i] = w5[i];
    if (tid < 32) sb[tid] = be[tid];
    __syncthreads();
    int b = blockIdx.x & 7, h = blockIdx.x >> 3, w = tid;
    const float* xp = x + (size_t)b * 65536;
    float xv[25];
    #pragma unroll
    for (int i = 0; i < 5; ++i) {
        int r = h + i - 2;
        #pragma unroll
        for (int j = 0; j < 5; ++j) {
            int c = w + j - 2;
            xv[i * 5 + j] = ((unsigned)r < 256u && (unsigned)c < 256u)
                            ? xp[r * 256 + c] : 0.f;
        }
    }
    u16* dst = out1 + ((size_t)b * HPW + (size_t)h * PW + PAD + w) * 32;
    #pragma unroll
    for (int cb = 0; cb < 4; ++cb) {
        short8 o;
        #pragma unroll
        for (int j = 0; j < 8; ++j) {
            int co = cb * 8 + j;
            float s = sb[co];
            #pragma unroll
            for (int t2 = 0; t2 < 25; ++t2) s = fmaf(sw[co * 25 + t2], xv[t2], s);
            s = (s > 0.f) ? s : 0.01f * s;
            o[j] = (short)f2bf(s);
        }
        *(short8*)(dst + cb * 8) = o;
    }
    if (tid < 24) {
        int col6 = tid >> 2, chunk = tid & 3;
        int col = (col6 < 3) ? col6 : (256 + PAD + col6 - 3);
        u16* pz = out1 + ((size_t)b * HPW + (size_t)h * PW + col) * 32 + chunk * 8;
        *(short8*)pz = (short8){0, 0, 0, 0, 0, 0, 0, 0};
    }
}

// ============ exact recompute of the 1-px ring ============================
__global__ __launch_bounds__(256) void ringfix_k(
    const float* __restrict__ x, const float* __restrict__ f4w,
    const float* __restrict__ f4b, const float* __restrict__ sbase,
    const float* __restrict__ sfac, const float* __restrict__ sbias,
    u16* __restrict__ out1)
{
    __shared__ float sW[288];
    __shared__ float sB[32];
    __shared__ float sF[32 * 33 * 9];
    __shared__ float sO[66][2][32];
    int tid = threadIdx.x;
    for (int i = tid; i < 288; i += 256) sW[i] = sbase[i] * sfac[i / 9];
    if (tid < 32) sB[tid] = sbias[tid];
    for (int i = tid; i < 32 * 33 * 9; i += 256) sF[i] = f4w[i];
    __syncthreads();

    int blk = blockIdx.x;
    int b = blk & 7, rest = blk >> 3;
    int e = rest >> 2, seg = rest & 3;
    const float* xp = x + (size_t)b * 65536;

    for (int i = tid; i < 66 * 2 * 32; i += 256) {
        int sc = i & 31, rr2 = i >> 5;
        int d = rr2 & 1, ul = rr2 >> 1;
        int ug = seg * 64 - 1 + ul;
        float v = 0.f;
        if ((unsigned)ug < 256u) {
            int h, w;
            if (e == 0)      { h = d;        w = ug; }
            else if (e == 1) { h = 255 - d;  w = ug; }
            else if (e == 2) { h = ug;       w = d; }
            else             { h = ug;       w = 255 - d; }
            float s = sB[sc];
            for (int p = 0; p < 3; ++p)
                for (int q = 0; q < 3; ++q) {
                    int rr = h + p - 1, cc = w + q - 1;
                    if ((unsigned)rr < 256u && (unsigned)cc < 256u)
                        s = fmaf(sW[sc * 9 + p * 3 + q], xp[rr * 256 + cc], s);
                }
            v = s;
        }
        sO[ul][d][sc] = v;
    }
    __syncthreads();

    int pi = tid & 63, cog = tid >> 6;
    int up = seg * 64 + pi;
    int h, w;
    if (e == 0)      { h = 0;   w = up; }
    else if (e == 1) { h = 255; w = up; }
    else if (e == 2) { h = up;  w = 0; }
    else             { h = up;  w = 255; }
    short8 ov;
    for (int cj = 0; cj < 8; ++cj) {
        int co = cog * 8 + cj;
        float acc = f4b[co];
        for (int a = 0; a < 3; ++a)
            for (int bb = 0; bb < 3; ++bb) {
                int hh = h + a - 1, ww = w + bb - 1;
                if ((unsigned)hh < 256u && (unsigned)ww < 256u)
                    acc = fmaf(sF[(co * 33) * 9 + a * 3 + bb], xp[hh * 256 + ww], acc);
                int d, ug;
                if (e == 0)      { d = hh;        ug = ww; }
                else if (e == 1) { d = 255 - hh;  ug = ww; }
                else if (e == 2) { d = ww;        ug = hh; }
                else             { d = 255 - ww;  ug = hh; }
                if (d >= 0 && d < 2 && (unsigned)ug < 256u) {
                    int ul = ug - (seg * 64 - 1);
                    for (int sc = 0; sc < 32; ++sc)
                        acc = fmaf(sF[(co * 33 + 1 + sc) * 9 + a * 3 + bb], sO[ul][d][sc], acc);
                }
            }
        acc = (acc > 0.f) ? acc : 0.01f * acc;
        ov[cj] = (short)f2bf(acc);
    }
    u16* dst = out1 + ((size_t)b * HPW + (size_t)h * PW + PAD + w) * 32 + cog * 8;
    *(short8*)dst = ov;
}

// ============ channel attention ===========================================
__global__ __launch_bounds__(256) void ca_part_k(
    const u16* __restrict__ enh, float* __restrict__ part)
{
    int blk = blockIdx.x, b = blk & 7, sl = blk >> 3;
    int tid = threadIdx.x, lane = tid & 63, wv = tid >> 6;
    float s[32], m[32];
    #pragma unroll
    for (int c = 0; c < 32; ++c) { s[c] = 0.f; m[c] = -1e30f; }
    for (int k = 0; k < 8; ++k) {
        int px = sl * 2048 + k * 256 + tid;
        int h = px >> 8, w = px & 255;
        size_t off = ((size_t)b * HPW + (size_t)h * PW + PAD + w) * 32;
        #pragma unroll
        for (int cb = 0; cb < 4; ++cb) {
            short8 v = *(const short8*)(enh + off + cb * 8);
            #pragma unroll
            for (int j = 0; j < 8; ++j) {
                float f = bf2f((u16)v[j]);
                s[cb * 8 + j] += f;
                m[cb * 8 + j] = fmaxf(m[cb * 8 + j], f);
            }
        }
    }
    #pragma unroll
    for (int c = 0; c < 32; ++c)
        #pragma unroll
        for (int o = 32; o; o >>= 1) {
            s[c] += __shfl_down(s[c], o);
            m[c] = fmaxf(m[c], __shfl_down(m[c], o));
        }
    __shared__ float ls[4][32], lm[4][32];
    if (lane == 0)
        for (int c = 0; c < 32; ++c) { ls[wv][c] = s[c]; lm[wv][c] = m[c]; }
    __syncthreads();
    if (tid < 32) {
        float ts = 0.f, tm = -1e30f;
        for (int w2 = 0; w2 < 4; ++w2) { ts += ls[w2][tid]; tm = fmaxf(tm, lm[w2][tid]); }
        int bs = b * 32 + sl;
        part[(size_t)(bs * 2 + 0) * 32 + tid] = ts;
        part[(size_t)(bs * 2 + 1) * 32 + tid] = tm;
    }
}

__global__ void ca_final_k(const float* __restrict__ part,
                           const float* __restrict__ w1, const float* __restrict__ w2,
                           float* __restrict__ ca)
{
    int t = threadIdx.x, b = t >> 5, c = t & 31;
    float s = 0.f, m = -1e30f;
    for (int sl = 0; sl < 32; ++sl) {
        int bs = b * 32 + sl;
        s += part[(size_t)(bs * 2 + 0) * 32 + c];
        m = fmaxf(m, part[(size_t)(bs * 2 + 1) * 32 + c]);
    }
    __shared__ float av[8][32], mx[8][32];
    av[b][c] = s * (1.f / 65536.f);
    mx[b][c] = m;
    __syncthreads();
    float sa0 = 0.f, sm0 = 0.f, sa1 = 0.f, sm1 = 0.f;
    for (int k = 0; k < 32; ++k) {
        float wa = w1[k], wb = w1[32 + k];
        sa0 = fmaf(wa, av[b][k], sa0); sm0 = fmaf(wa, mx[b][k], sm0);
        sa1 = fmaf(wb, av[b][k], sa1); sm1 = fmaf(wb, mx[b][k], sm1);
    }
    float h0 = fmaxf(sa0, 0.f) + fmaxf(sm0, 0.f);
    float h1 = fmaxf(sa1, 0.f) + fmaxf(sm1, 0.f);
    ca[t] = sigm(w2[c * 2 + 0] * h0 + w2[c * 2 + 1] * h1);
}

// ============ SA input maps (padded 262x262) ==============================
__global__ __launch_bounds__(256) void samap_k(
    const u16* __restrict__ enh, const float* __restrict__ ca,
    float* __restrict__ smap)
{
    __shared__ float sca[256];
    int tid = threadIdx.x;
    sca[tid] = ca[tid];
    __syncthreads();
    int b = blockIdx.x & 7;
    int r = (blockIdx.x >> 3) * 256 + tid;
    if (r >= 262 * 262) return;
    int ph = r / 262, pw = r % 262;
    float mean = 0.f, mxv = 0.f;
    if (ph >= 3 && ph < 259 && pw >= 3 && pw < 259) {
        int h = ph - 3, w = pw - 3;
        size_t off = ((size_t)b * HPW + (size_t)h * PW + PAD + w) * 32;
        float s = 0.f, m = -1e30f;
        #pragma unroll
        for (int cb = 0; cb < 4; ++cb) {
            short8 v = *(const short8*)(enh + off + cb * 8);
            #pragma unroll
            for (int j = 0; j < 8; ++j) {
                float f = bf2f((u16)v[j]) * sca[b * 32 + cb * 8 + j];
                s += f; m = fmaxf(m, f);
            }
        }
        mean = s * (1.f / 32.f); mxv = m;
    }
    smap[((size_t)b * 262 * 262 + (size_t)ph * 262 + pw) * 2 + 0] = mean;
    smap[((size_t)b * 262 * 262 + (size_t)ph * 262 + pw) * 2 + 1] = mxv;
}

// ============ 7x7 SA conv + merge + fused p1 (1x1 via MFMA) ===============
__global__ __launch_bounds__(256) void merge_k(
    const float* __restrict__ smap, const float* __restrict__ saw,
    const float* __restrict__ ca, const u16* __restrict__ out1,
    const u16* __restrict__ enh, u16* __restrict__ o0,
    float* __restrict__ dout,
    const u16* __restrict__ ap1, const float* __restrict__ p1b,
    u16* __restrict__ p1out)
{
    __shared__ float sw[98];
    __shared__ float sca[256];
    __shared__ u16 tile[256 * 32];   // out0 bf16 tile, 16 KB
    int tid = threadIdx.x;
    for (int i = tid; i < 98; i += 256) sw[i] = saw[i];
    sca[tid] = ca[tid];
    __syncthreads();
    int b = blockIdx.x & 7;
    int h = blockIdx.x >> 3;
    int w = tid;
    const float* sp = smap + (size_t)b * 262 * 262 * 2;
    float acc = 0.f;
    #pragma unroll
    for (int kh = 0; kh < 7; ++kh)
        #pragma unroll
        for (int kw = 0; kw < 7; ++kw) {
            const float* q = sp + ((size_t)(h + kh) * 262 + (w + kw)) * 2;
            acc = fmaf(q[0], sw[kh * 7 + kw], acc);
            acc = fmaf(q[1], sw[49 + kh * 7 + kw], acc);
        }
    float sa = sigm(acc);
    size_t off = ((size_t)b * HPW + (size_t)h * PW + PAD + w) * 32;
    float* dp = dout + (size_t)b * 64 * 65536 + (size_t)h * 256 + w;
    #pragma unroll
    for (int cb = 0; cb < 4; ++cb) {
        short8 ve = *(const short8*)(enh + off + cb * 8);
        short8 vo = *(const short8*)(out1 + off + cb * 8);
        short8 o;
        #pragma unroll
        for (int j = 0; j < 8; ++j) {
            float f = sca[b * 32 + cb * 8 + j] * bf2f((u16)ve[j]);
            float v = bf2f((u16)vo[j]) + sa * f;
            v = (v > 0.f) ? v : 0.01f * v;
            o[j] = (short)f2bf(v);
            dp[(size_t)(cb * 8 + j) * 65536] = v;
        }
        *(short8*)(o0 + off + cb * 8) = o;
        *(short8*)(&tile[w * 32 + cb * 8]) = o;
    }
    __syncthreads();
    // fused p1: 1x1 over out0 tile, K=32 single step
    const int lane = tid & 63, wv = tid >> 6;
    const int icg = lane >> 4, l15 = lane & 15;
    f32x4 acc1[2][4];
    #pragma unroll
    for (int mf = 0; mf < 2; ++mf)
        #pragma unroll
        for (int nf = 0; nf < 4; ++nf)
            acc1[mf][nf] = (f32x4){0.f, 0.f, 0.f, 0.f};
    short8 pa0 = *(const short8*)(ap1 + (size_t)0 * 512 + lane * 8);
    short8 pa1 = *(const short8*)(ap1 + (size_t)1 * 512 + lane * 8);
    #pragma unroll
    for (int nf = 0; nf < 4; ++nf) {
        short8 bf = *(const short8*)(&tile[(wv * 64 + l15 + nf * 16) * 32 + icg * 8]);
        acc1[0][nf] = __builtin_amdgcn_mfma_f32_16x16x32_bf16(pa0, bf, acc1[0][nf], 0, 0, 0);
        acc1[1][nf] = __builtin_amdgcn_mfma_f32_16x16x32_bf16(pa1, bf, acc1[1][nf], 0, 0, 0);
    }
    const size_t orow = ((size_t)b * HPW + (size_t)h * PW + PAD) * 32;
    #pragma unroll
    for (int mf = 0; mf < 2; ++mf) {
        const int cob = mf * 16 + icg * 4;
        f32x4 pbi = *(const f32x4*)(p1b + cob);
        #pragma unroll
        for (int nf = 0; nf < 4; ++nf) {
            const int px = wv * 64 + l15 + nf * 16;
            ushort4v o;
            #pragma unroll
            for (int i = 0; i < 4; ++i) {
                float v = acc1[mf][nf][i] + pbi[i];
                v = (v > 0.f) ? v : 0.01f * v;
                o[i] = f2bf(v);
            }
            *(ushort4v*)(p1out + orow + (size_t)px * 32 + cob) = o;
        }
    }
}

extern "C" void kernel_launch(void* const* d_in, const int* in_sizes, int n_in,
                              void* d_out, int out_size, void* d_ws, size_t ws_size,
                              hipStream_t stream)
{
    (void)in_sizes; (void)n_in; (void)out_size; (void)ws_size;
    const float* x        = (const float*)d_in[0];
    const float* sob_base = (const float*)d_in[1];
    const float* sob_fac  = (const float*)d_in[2];
    const float* sob_bias = (const float*)d_in[3];
    const float* f4_w = (const float*)d_in[4];   const float* f4_b = (const float*)d_in[5];
    const float* ec1_w = (const float*)d_in[6];  const float* ec1_b = (const float*)d_in[7];
    const float* ec2_w = (const float*)d_in[8];  const float* ec2_b = (const float*)d_in[9];
    const float* ec3_w = (const float*)d_in[10]; const float* ec3_b = (const float*)d_in[11];
    const float* gate_w = (const float*)d_in[12]; const float* gate_b = (const float*)d_in[13];
    const float* ca1_w = (const float*)d_in[14]; const float* ca2_w = (const float*)d_in[15];
    const float* sa_w  = (const float*)d_in[16];
    const float* p1_w = (const float*)d_in[17]; const float* p1_b = (const float*)d_in[18];
    const float* f1_w = (const float*)d_in[19]; const float* f1_b = (const float*)d_in[20];
    const float* p2_w = (const float*)d_in[21]; const float* p2_b = (const float*)d_in[22];
    const float* f2_w = (const float*)d_in[23]; const float* f2_b = (const float*)d_in[24];
    const float* p3_w = (const float*)d_in[25]; const float* p3_b = (const float*)d_in[26];
    const float* f3_w = (const float*)d_in[27]; const float* f3_b = (const float*)d_in[28];

    const size_t PB32 = (size_t)Bb * HPW * 32 * 2;
    char* ws = (char*)d_ws;
    u16* Q    = (u16*)(ws);
    u16* O0   = (u16*)(ws + PB32);
    u16* T    = (u16*)(ws + 2 * PB32);
    u16* ENH  = (u16*)(ws + 3 * PB32);
    u16* AP   = (u16*)(ws + 4 * PB32);
    float* W5   = (float*)(ws + 4 * PB32 + 77 * 1024 * 2);
    float* BE   = W5 + 800;
    float* PART = BE + 32;
    float* CA   = PART + 8 * 32 * 2 * 32;

    char* doutc = (char*)d_out;
    float* SMAP = (float*)(doutc + (134217728 - (size_t)Bb * 262 * 262 * 2 * 4));
    float* dout = (float*)d_out;

    dim3 blk(256);

    prepack_k<<<308, blk, 0, stream>>>(f4_w, ec1_w, ec2_w, ec3_w, f1_w, f2_w, f3_w,
                                       p1_w, p2_w, p3_w, AP);
    prep5_k<<<1, blk, 0, stream>>>(f4_w, f4_b, sob_base, sob_fac, sob_bias, W5, BE);
    conv5_k<<<2048, blk, 0, stream>>>(x, W5, BE, Q);
    ringfix_k<<<128, blk, 0, stream>>>(x, f4_w, f4_b, sob_base, sob_fac, sob_bias, Q);
    ecfuse_k<<<4096, blk, 0, stream>>>(Q, AP + 18 * 1024, ec1_b, ec2_b, ec3_b,
                                       gate_w, gate_b, ENH);
    ca_part_k<<<256, blk, 0, stream>>>(ENH, PART);
    ca_final_k<<<1, blk, 0, stream>>>(PART, ca1_w, ca2_w, CA);
    samap_k<<<2152, blk, 0, stream>>>(ENH, CA, SMAP);
    merge_k<<<2048, blk, 0, stream>>>(SMAP, sa_w, CA, Q, ENH, O0, dout,
                                      AP + 72 * 1024, p1_b, Q);
    convs_k<2, false, true ><<<2048, blk, 0, stream>>>(Q, AP + 45 * 1024, f1_b, nullptr,
                                                       O0, AP + 73 * 1024, p2_b, T);
    convs_k<2, false, true ><<<2048, blk, 0, stream>>>(T, AP + 54 * 1024, f2_b, nullptr,
                                                       O0, AP + 75 * 1024, p3_b, Q);
    convs_k<2, true, false><<<2048, blk, 0, stream>>>(Q, AP + 63 * 1024, f3_b, dout,
                                                      nullptr, nullptr, nullptr, nullptr);
}